// Round 3
// baseline (217.238 us; speedup 1.0000x reference)
//
#include <hip/hip_runtime.h>
#include <cstdint>
#include <cstddef>

#define BB 16
#define PP 19248
#define NOBJ 32
#define NCLS 81
#define POS_TH 0.5f
#define NEG_TH 0.4f
#define VAR0 0.1f
#define VAR1 0.2f
#define NEGPOS 3

#define MTB 256
#define NMB ((PP + MTB - 1) / MTB)    // 76
#define MAINB 1024
#define ROWS_PB 64                     // rows per k_main block (4 rows/wave * 16 waves)
#define NSLOT ((PP + ROWS_PB - 1) / ROWS_PB)   // 301
#define ST 1024

// histogram select parameters
#define HSHIFT 19
#define HSIZE 8192                     // bins = bits >> 19 (13 bits)
#define HPT (HSIZE / ST)               // 8 bins per thread
#define CAP HSIZE                      // collection buffer reuses hist LDS

// ---------------- match: per-gt best prior ONLY (gkey); no bulk stores ----------------
__global__ __launch_bounds__(MTB) void k_match(const float* __restrict__ priors,
                                               const float* __restrict__ gt_boxes,
                                               unsigned long long* __restrict__ gkey) {
    const int b = blockIdx.y;
    const int p = blockIdx.x * MTB + threadIdx.x;
    const int wid = threadIdx.x >> 6, lane = threadIdx.x & 63;
    __shared__ float4 sg[NOBJ];
    __shared__ unsigned long long wkey[4][NOBJ];
    if (threadIdx.x < NOBJ) sg[threadIdx.x] = ((const float4*)gt_boxes)[b * NOBJ + threadIdx.x];
    __syncthreads();

    const bool valid = p < PP;
    float px1 = 0.f, py1 = 0.f, px2 = 0.f, py2 = 0.f, parea = 0.f;
    if (valid) {
        float4 pr = ((const float4*)priors)[p];
        float hw = pr.z / 2.0f, hh = pr.w / 2.0f;
        px1 = pr.x - hw; py1 = pr.y - hh; px2 = pr.x + hw; py2 = pr.y + hh;
        parea = (px2 - px1) * (py2 - py1);
    }

    for (int n = 0; n < NOBJ; ++n) {
        float4 g = sg[n];
        float iou = -1.0f;   // invalid lanes lose every comparison
        if (valid) {
            {
#pragma clang fp contract(off)
                float ix1 = fmaxf(g.x, px1), iy1 = fmaxf(g.y, py1);
                float ix2 = fminf(g.z, px2), iy2 = fminf(g.w, py2);
                float iw = fmaxf(ix2 - ix1, 0.0f), ih = fmaxf(iy2 - iy1, 0.0f);
                float inter = iw * ih;
                float garea = (g.z - g.x) * (g.w - g.y);
                iou = inter / (garea + parea - inter);
            }
        }

        // wave-level max + first-index pick (strict first-max via lowest lane)
        float m = iou;
        m = fmaxf(m, __shfl_xor(m, 1, 64));
        m = fmaxf(m, __shfl_xor(m, 2, 64));
        m = fmaxf(m, __shfl_xor(m, 4, 64));
        m = fmaxf(m, __shfl_xor(m, 8, 64));
        m = fmaxf(m, __shfl_xor(m, 16, 64));
        m = fmaxf(m, __shfl_xor(m, 32, 64));
        unsigned long long ball = __ballot(iou == m);
        if (lane == 0) {
            unsigned long long key = 0ull;
            if (m >= 0.0f) {   // wave had at least one valid lane
                unsigned psrc = (unsigned)(blockIdx.x * MTB + wid * 64 +
                                           (int)__builtin_ctzll(ball));
                key = (((unsigned long long)__float_as_uint(m)) << 32) |
                      (unsigned long long)(0xFFFFFFFFu - psrc);
            }
            wkey[wid][n] = key;
        }
    }

    __syncthreads();
    if (threadIdx.x < NOBJ) {
        unsigned long long k0 = wkey[0][threadIdx.x];
        unsigned long long k1 = wkey[1][threadIdx.x];
        unsigned long long k2 = wkey[2][threadIdx.x];
        unsigned long long k3 = wkey[3][threadIdx.x];
        if (k1 > k0) k0 = k1;
        if (k2 > k0) k0 = k2;
        if (k3 > k0) k0 = k3;
        atomicMax(&gkey[b * NOBJ + threadIdx.x], k0);
    }
}

__device__ __forceinline__ float sl1(float d) {
    float ad = fabsf(d);
    return ad < 1.0f ? 0.5f * d * d : ad - 0.5f;
}

// ---------------- main: fused per-row match + 16-lane logsumexp; no bto/bti round-trip ----------------
// wave = 4 rows (16 lanes each); block = 16 waves = 64 rows.
__global__ __launch_bounds__(MAINB, 8) void k_main(const float* __restrict__ loc_data,
                                                   const float* __restrict__ conf_data,
                                                   const float* __restrict__ priors,
                                                   const float* __restrict__ gt_boxes,
                                                   const int* __restrict__ gt_labels,
                                                   const unsigned long long* __restrict__ gkey,
                                                   float* __restrict__ mine,
                                                   float* __restrict__ p_ll,
                                                   float* __restrict__ p_lc,
                                                   int* __restrict__ p_np) {
    const int b = blockIdx.y;
    const int t = threadIdx.x;
    const int wid = t >> 6;            // 0..15
    const int lane = t & 63;
    const int g = lane >> 4;           // row-group within wave: 0..3
    const int j = lane & 15;           // lane within row-group
    const int rbase = blockIdx.x * ROWS_PB + wid * 4;   // wave's first row
    const int r = rbase + g;           // this lane's row (whole waves valid/invalid: PP % 4 == 0)
    const bool valid = r < PP;

    // lanes 0..31 hold the 32 forced-prior indices for this batch
    unsigned pst = 0xFFFFFFFFu;
    if (lane < NOBJ) {
        unsigned long long key = gkey[b * NOBJ + lane];
        pst = 0xFFFFFFFFu - (unsigned)(key & 0xFFFFFFFFull);
    }

    // issue conf loads early (latency hidden under IoU work below)
    const float* rowp = conf_data + ((size_t)b * PP + r) * NCLS;
    float c0 = 0.f, c1 = 0.f, c2 = 0.f, c3 = 0.f, c4 = 0.f, c80 = 0.f;
    float4 pr = make_float4(0.f, 0.f, 0.f, 0.f);
    if (valid) {
        c0 = rowp[j];
        c1 = rowp[j + 16];
        c2 = rowp[j + 32];
        c3 = rowp[j + 48];
        c4 = rowp[j + 64];
        if (j == 0) c80 = rowp[80];
        pr = ((const float4*)priors)[r];
    }
    // per-row best-gt: lane j handles objects j and j+16 (coalesced 512 B, L1-broadcast)
    float4 ga = ((const float4*)gt_boxes)[b * NOBJ + j];
    float4 gb = ((const float4*)gt_boxes)[b * NOBJ + j + 16];
    float bov;
    int bidx;
    {
#pragma clang fp contract(off)
        float hw = pr.z / 2.0f, hh = pr.w / 2.0f;
        float px1 = pr.x - hw, py1 = pr.y - hh, px2 = pr.x + hw, py2 = pr.y + hh;
        float parea = (px2 - px1) * (py2 - py1);

        float ix1 = fmaxf(ga.x, px1), iy1 = fmaxf(ga.y, py1);
        float ix2 = fminf(ga.z, px2), iy2 = fminf(ga.w, py2);
        float iw = fmaxf(ix2 - ix1, 0.0f), ih = fmaxf(iy2 - iy1, 0.0f);
        float inter = iw * ih;
        float garea = (ga.z - ga.x) * (ga.w - ga.y);
        float iouA = inter / (garea + parea - inter);

        ix1 = fmaxf(gb.x, px1); iy1 = fmaxf(gb.y, py1);
        ix2 = fminf(gb.z, px2); iy2 = fminf(gb.w, py2);
        iw = fmaxf(ix2 - ix1, 0.0f); ih = fmaxf(iy2 - iy1, 0.0f);
        inter = iw * ih;
        garea = (gb.z - gb.x) * (gb.w - gb.y);
        float iouB = inter / (garea + parea - inter);

        bov = iouA; bidx = j;                      // tie -> smaller index (first-max)
        if (iouB > bov) { bov = iouB; bidx = j + 16; }
    }
    // argmax reduce across the 16-lane group: larger ov wins; tie -> smaller index
#pragma unroll
    for (int m = 1; m < 16; m <<= 1) {
        float o = __shfl_xor(bov, m, 64);
        int oi = __shfl_xor(bidx, m, 64);
        if (o > bov || (o == bov && oi < bidx)) { bov = o; bidx = oi; }
    }

    // parallel logsumexp
    float s = __expf(c0) + __expf(c1) + __expf(c2) + __expf(c3) + __expf(c4);
    if (j == 0) s += __expf(c80);
    s += __shfl_xor(s, 1, 64);
    s += __shfl_xor(s, 2, 64);
    s += __shfl_xor(s, 4, 64);
    s += __shfl_xor(s, 8, 64);
    const float lse = __logf(s);

    // forced-positive: one ballot per row against the 32 pstars; last-wins = highest set bit
    unsigned long long b0 = __ballot(pst == (unsigned)(rbase + 0));
    unsigned long long b1 = __ballot(pst == (unsigned)(rbase + 1));
    unsigned long long b2 = __ballot(pst == (unsigned)(rbase + 2));
    unsigned long long b3 = __ballot(pst == (unsigned)(rbase + 3));
    unsigned long long mball = (g == 0) ? b0 : (g == 1) ? b1 : (g == 2) ? b2 : b3;

    float my_ll = 0.0f, my_lc = 0.0f;
    int my_pos = 0;

    if (valid && j == 0) {
        const size_t idx = (size_t)b * PP + r;
        float ov = bov;
        int ti = bidx;
        if (mball) { ov = 2.0f; ti = 63 - __builtin_clzll(mball); }
        int conf_c = gt_labels[b * NOBJ + ti] + 1;
        if (ov < POS_TH) conf_c = -1;
        if (ov < NEG_TH) conf_c = 0;
        const int ct = conf_c > 0 ? conf_c : 0;
        const float nll = lse - rowp[ct];

        if (conf_c > 0) {
            my_pos = 1;
            my_lc = nll;
            float4 gbox = ((const float4*)gt_boxes)[b * NOBJ + ti];
            float mcx = (gbox.x + gbox.z) / 2.0f, mcy = (gbox.y + gbox.w) / 2.0f;
            float mw = gbox.z - gbox.x, mh = gbox.w - gbox.y;
            float t0 = (mcx - pr.x) / (VAR0 * pr.z);
            float t1 = (mcy - pr.y) / (VAR0 * pr.w);
            float t2 = logf(mw / pr.z) / VAR1;
            float t3 = logf(mh / pr.w) / VAR1;
            float4 ld = ((const float4*)loc_data)[(size_t)b * PP + r];
            my_ll = sl1(ld.x - t0) + sl1(ld.y - t1) + sl1(ld.z - t2) + sl1(ld.w - t3);
        }
        mine[idx] = (conf_c == 0) ? nll : 0.0f;
    }

    // block reduce: per-wave shfl tree -> 16 LDS slots -> thread 0 writes plain slot stores
    for (int off = 32; off > 0; off >>= 1) {
        my_ll += __shfl_down(my_ll, off, 64);
        my_lc += __shfl_down(my_lc, off, 64);
        my_pos += __shfl_down(my_pos, off, 64);
    }
    __shared__ float rll[16], rlc[16];
    __shared__ int rnp[16];
    if (lane == 0) { rll[wid] = my_ll; rlc[wid] = my_lc; rnp[wid] = my_pos; }
    __syncthreads();
    if (t == 0) {
        float a = 0.0f, c = 0.0f;
        int n = 0;
#pragma unroll
        for (int w = 0; w < 16; ++w) { a += rll[w]; c += rlc[w]; n += rnp[w]; }
        p_ll[b * NSLOT + blockIdx.x] = a;
        p_lc[b * NSLOT + blockIdx.x] = c;
        p_np[b * NSLOT + blockIdx.x] = n;
    }
}

// ---------------- select: histogram top-k (2 global scans) + LDS refine + fused finalize ----------------
__global__ __launch_bounds__(ST) void k_select(const float* __restrict__ mine,
                                               const float* __restrict__ p_ll,
                                               const float* __restrict__ p_lc,
                                               const int* __restrict__ p_np,
                                               float* __restrict__ acc,
                                               int* __restrict__ acc_np,
                                               unsigned* __restrict__ done,
                                               float* __restrict__ out) {
    const int b = blockIdx.x;
    const int tid = threadIdx.x;
    const int wid = tid >> 6, lane = tid & 63;
    constexpr int NW = ST / 64;

    __shared__ unsigned hist[HSIZE];           // 32 KB; reused as collection buffer
    __shared__ unsigned s_tsum[ST];            // 4 KB
    __shared__ unsigned s_wsum[NW];
    __shared__ float rll[NW], rlc[NW];
    __shared__ int rnp[NW];
    __shared__ float rs1[NW], rs2[NW];
    __shared__ unsigned rc2[NW];
    __shared__ float s_ll, s_lc, s_neg;
    __shared__ int s_np, s_B, s_G1;
    __shared__ unsigned s_cntB, s_cnt, s_prefix;
    __shared__ int s_rem;
    __shared__ unsigned h16[16];
    // fallback radix shared state
    __shared__ unsigned swh[NW * 16];
    __shared__ unsigned stot[16];

    // ---- 1. reduce this batch's partial slots ----
    float ll = 0.0f, lc = 0.0f;
    int np = 0;
    for (int i = tid; i < NSLOT; i += ST) {
        ll += p_ll[b * NSLOT + i];
        lc += p_lc[b * NSLOT + i];
        np += p_np[b * NSLOT + i];
    }
    for (int off = 32; off > 0; off >>= 1) {
        ll += __shfl_down(ll, off, 64);
        lc += __shfl_down(lc, off, 64);
        np += __shfl_down(np, off, 64);
    }
    if (lane == 0) { rll[wid] = ll; rlc[wid] = lc; rnp[wid] = np; }
    __syncthreads();
    if (tid == 0) {
        float a = 0.0f, c = 0.0f;
        int n = 0;
        for (int w = 0; w < NW; ++w) { a += rll[w]; c += rlc[w]; n += rnp[w]; }
        s_ll = a; s_lc = c; s_np = n;
        s_neg = 0.0f;
    }
    __syncthreads();
    const int np_b = s_np;
    const int k = min(NEGPOS * np_b, PP - 1);

    const float* mv = mine + (size_t)b * PP;
    const float4* mv4 = (const float4*)mv;
    constexpr int PP4 = PP / 4;   // 4812

    if (k > 0) {
        // ---- 2. scan 1: 8192-bin LDS histogram of bits>>19 (float4 loads, pipelined) ----
        for (int i = tid; i < HSIZE; i += ST) hist[i] = 0u;
        __syncthreads();
        for (int i = tid; i < PP4; i += ST) {
            float4 v = mv4[i];
            atomicAdd(&hist[__float_as_uint(v.x) >> HSHIFT], 1u);
            atomicAdd(&hist[__float_as_uint(v.y) >> HSHIFT], 1u);
            atomicAdd(&hist[__float_as_uint(v.z) >> HSHIFT], 1u);
            atomicAdd(&hist[__float_as_uint(v.w) >> HSHIFT], 1u);
        }
        __syncthreads();

        // ---- 3. find boundary bin B (suffix scan from top: waves -> threads -> bins) ----
        unsigned tsum = 0;
        const int hb = tid * HPT;
#pragma unroll
        for (int v = 0; v < HPT; ++v) tsum += hist[hb + v];
        s_tsum[tid] = tsum;
        unsigned wsum = tsum;
        for (int off = 32; off > 0; off >>= 1) wsum += __shfl_down(wsum, off, 64);
        if (lane == 0) s_wsum[wid] = wsum;
        __syncthreads();
        if (tid == 0) {
            unsigned cum = 0;
            int w = NW - 1;
            for (; w > 0; --w) {
                if (cum + s_wsum[w] >= (unsigned)k) break;
                cum += s_wsum[w];
            }
            int t = (w + 1) * 64 - 1;
            for (; t > w * 64; --t) {
                if (cum + s_tsum[t] >= (unsigned)k) break;
                cum += s_tsum[t];
            }
            int bin = t * HPT + HPT - 1;
            for (; bin > t * HPT; --bin) {
                if (cum + hist[bin] >= (unsigned)k) break;
                cum += hist[bin];
            }
            s_B = bin;
            s_G1 = (int)cum;          // count strictly above bin B
            s_cntB = hist[bin];
            s_cnt = 0u;
        }
        __syncthreads();
        const int B = s_B;
        const int r = k - s_G1;                         // 1 <= r <= cntB
        const unsigned cntB = s_cntB;
        const unsigned bin_lo = (unsigned)B << HSHIFT;
        const unsigned hi_base = (unsigned)(B + 1) << HSHIFT;
        unsigned* cbuf = hist;                          // reuse (all hist reads are done)

        if (cntB <= CAP) {
            // ---- 4. scan 2: exact sum above bin B + collect bin-B elements into LDS ----
            float S1 = 0.0f;
            for (int i = tid; i < PP4; i += ST) {
                float4 v = mv4[i];
                unsigned bx = __float_as_uint(v.x);
                unsigned by = __float_as_uint(v.y);
                unsigned bz = __float_as_uint(v.z);
                unsigned bw = __float_as_uint(v.w);
                if (bx >= hi_base) S1 += v.x;
                else if (bx >= bin_lo) cbuf[atomicAdd(&s_cnt, 1u)] = bx;
                if (by >= hi_base) S1 += v.y;
                else if (by >= bin_lo) cbuf[atomicAdd(&s_cnt, 1u)] = by;
                if (bz >= hi_base) S1 += v.z;
                else if (bz >= bin_lo) cbuf[atomicAdd(&s_cnt, 1u)] = bz;
                if (bw >= hi_base) S1 += v.w;
                else if (bw >= bin_lo) cbuf[atomicAdd(&s_cnt, 1u)] = bw;
            }
            for (int off = 32; off > 0; off >>= 1) S1 += __shfl_down(S1, off, 64);
            if (lane == 0) rs1[wid] = S1;
            __syncthreads();   // also fences the collection writes

            // ---- 5. refine low 19 bits among the cntB collected elements (LDS-resident) ----
            if (tid == 0) { s_prefix = bin_lo; s_rem = r; }
            __syncthreads();
            for (int pass = 0; pass < 5; ++pass) {
                const int shift = (pass < 4) ? (15 - 4 * pass) : 0;
                const int width = (pass < 4) ? 4 : 3;
                const int nb = 1 << width;
                const unsigned hm = 0xFFFFFFFFu << (shift + width);
                if (tid < 16) h16[tid] = 0u;
                __syncthreads();
                const unsigned prefix = s_prefix;
                for (unsigned i = tid; i < cntB; i += ST) {
                    unsigned bits = cbuf[i];
                    if ((bits & hm) == prefix)
                        atomicAdd(&h16[(bits >> shift) & (nb - 1)], 1u);
                }
                __syncthreads();
                if (tid == 0) {
                    int rem = s_rem;
                    unsigned cum = 0;
                    int chosen = 0;
                    for (int v = nb - 1; v >= 0; --v) {
                        unsigned c = h16[v];
                        if (cum + c >= (unsigned)rem) { chosen = v; s_rem = rem - (int)cum; break; }
                        cum += c;
                    }
                    s_prefix = prefix | ((unsigned)chosen << shift);
                }
                __syncthreads();
            }
            const unsigned T = s_prefix;   // exact bits of the r-th largest within bin B

            // ---- 6. final: sum collected > T, tie-fill with T ----
            float S2 = 0.0f;
            unsigned c2 = 0;
            for (unsigned i = tid; i < cntB; i += ST) {
                unsigned bits = cbuf[i];
                if (bits > T) { S2 += __uint_as_float(bits); c2++; }
            }
            for (int off = 32; off > 0; off >>= 1) {
                S2 += __shfl_down(S2, off, 64);
                c2 += __shfl_down(c2, off, 64);
            }
            if (lane == 0) { rs2[wid] = S2; rc2[wid] = c2; }
            __syncthreads();
            if (tid == 0) {
                float S1t = 0.0f, S2t = 0.0f;
                unsigned c2t = 0;
                for (int w = 0; w < NW; ++w) { S1t += rs1[w]; S2t += rs2[w]; c2t += rc2[w]; }
                s_neg = S1t + S2t + (float)(r - (int)c2t) * __uint_as_float(T);
            }
            __syncthreads();
        } else {
            // ---- fallback (collection overflow — practically unreachable): old 8-pass global radix ----
            if (tid == 0) { s_prefix = 0u; s_rem = k; }
            __syncthreads();
            for (int pass = 0; pass < 8; ++pass) {
                const int shift = 28 - 4 * pass;
                const unsigned hm = (pass == 0) ? 0u : (0xFFFFFFFFu << (shift + 4));
                const unsigned prefix = s_prefix;
                unsigned cnt[16];
#pragma unroll
                for (int v = 0; v < 16; ++v) cnt[v] = 0u;
                for (int i = tid; i < PP; i += ST) {
                    unsigned bits = __float_as_uint(mv[i]);
                    unsigned key = ((bits & hm) == prefix) ? ((bits >> shift) & 15u) : 16u;
                    if (__any(key != 16u)) {
#pragma unroll
                        for (int v = 0; v < 16; ++v)
                            cnt[v] += (unsigned)__popcll(__ballot(key == (unsigned)v));
                    }
                }
                if (lane == 0) {
#pragma unroll
                    for (int v = 0; v < 16; ++v) swh[wid * 16 + v] = cnt[v];
                }
                __syncthreads();
                if (tid < 16) {
                    unsigned tt = 0;
#pragma unroll
                    for (int w = 0; w < NW; ++w) tt += swh[w * 16 + tid];
                    stot[tid] = tt;
                }
                __syncthreads();
                if (tid == 0) {
                    int rem = s_rem;
                    unsigned cum = 0;
                    int chosen = 0;
                    for (int v = 15; v >= 0; --v) {
                        unsigned c = stot[v];
                        if (cum + c >= (unsigned)rem) { chosen = v; s_rem = rem - (int)cum; break; }
                        cum += c;
                    }
                    s_prefix = prefix | ((unsigned)chosen << shift);
                }
                __syncthreads();
            }
            const unsigned T = s_prefix;
            float sum = 0.0f;
            unsigned cnt = 0;
            for (int i = tid; i < PP; i += ST) {
                float v = mv[i];
                if (__float_as_uint(v) > T) { sum += v; cnt++; }
            }
            for (int off = 32; off > 0; off >>= 1) {
                sum += __shfl_down(sum, off, 64);
                cnt += __shfl_down(cnt, off, 64);
            }
            if (lane == 0) { rs2[wid] = sum; rc2[wid] = cnt; }
            __syncthreads();
            if (tid == 0) {
                float S = 0.0f;
                int G = 0;
                for (int w = 0; w < NW; ++w) { S += rs2[w]; G += (int)rc2[w]; }
                s_neg = S + (float)(k - G) * __uint_as_float(T);
            }
            __syncthreads();
        }
    }

    if (tid == 0) {
        atomicAdd(&acc[0], s_ll);
        atomicAdd(&acc[1], s_lc + s_neg);
        atomicAdd(acc_np, np_b);
        __threadfence();
        unsigned prev = atomicAdd(done, 1u);
        if (prev == BB - 1) {
            int tp = atomicAdd(acc_np, 0);
            float N = (float)max(tp, 1);
            float a0 = atomicAdd(&acc[0], 0.0f);
            float a1 = atomicAdd(&acc[1], 0.0f);
            out[0] = a0 / N;
            out[1] = a1 / N;
        }
    }
}

extern "C" void kernel_launch(void* const* d_in, const int* in_sizes, int n_in,
                              void* d_out, int out_size, void* d_ws, size_t ws_size,
                              hipStream_t stream) {
    const float* loc    = (const float*)d_in[0];
    const float* conf   = (const float*)d_in[1];
    const float* priors = (const float*)d_in[2];
    const float* gt     = (const float*)d_in[3];
    const int*   labels = (const int*)d_in[4];
    float* out = (float*)d_out;

    char* ws = (char*)d_ws;
    const size_t SZ_BP = (size_t)BB * PP * 4;        // 1,231,872 B
    const size_t SZ_SLOT = (size_t)BB * NSLOT * 4;   // 19,264 B
    // [0,4096) gkey | [4096,4104) acc | [4104,4108) acc_np | [4108,4112) done | pad 4224
    unsigned long long* gkey = (unsigned long long*)ws;
    float*    acc    = (float*)   (ws + 4096);
    int*      acc_np = (int*)     (ws + 4104);
    unsigned* done   = (unsigned*)(ws + 4108);
    float* mine = (float*)(ws + 4224);
    float* p_ll = (float*)(ws + 4224 + SZ_BP);
    float* p_lc = (float*)(ws + 4224 + SZ_BP + SZ_SLOT);
    int*   p_np = (int*)  (ws + 4224 + SZ_BP + 2 * SZ_SLOT);

    (void)hipMemsetAsync(ws, 0, 4224, stream);   // gkey + acc + acc_np + done

    dim3 mg(NMB, BB);
    k_match<<<mg, MTB, 0, stream>>>(priors, gt, gkey);

    dim3 kg(NSLOT, BB);
    k_main<<<kg, MAINB, 0, stream>>>(loc, conf, priors, gt, labels, gkey,
                                     mine, p_ll, p_lc, p_np);

    k_select<<<BB, ST, 0, stream>>>(mine, p_ll, p_lc, p_np, acc, acc_np, done, out);
}

// Round 4
// 213.583 us; speedup vs baseline: 1.0171x; 1.0171x over previous
//
#include <hip/hip_runtime.h>
#include <cstdint>
#include <cstddef>

#define BB 16
#define PP 19248
#define NOBJ 32
#define NCLS 81
#define POS_TH 0.5f
#define NEG_TH 0.4f
#define VAR0 0.1f
#define VAR1 0.2f
#define NEGPOS 3

#define MTB 256
#define NMB ((PP + MTB - 1) / MTB)    // 76
#define MAINB 1024
#define ROWS_PB 64                     // rows per k_main block (4 rows/wave * 16 waves)
#define NSLOT ((PP + ROWS_PB - 1) / ROWS_PB)   // 301 blocks/batch
#define NSLOTW (NSLOT * 16)            // 4816 per-wave slots/batch
#define ST 1024

// object-parallel match parameters
#define MCH 8                          // prior chunks per object
#define CHLEN (PP / MCH)               // 2406 (exact)
#define MJOBS (BB * NOBJ * MCH)        // 4096 wave-jobs
#define MBLK (MJOBS / 4)               // 1024 blocks of 4 waves

// histogram select parameters
#define HSHIFT 19
#define HSIZE 8192                     // bins = bits >> 19 (13 bits)
#define HPT (HSIZE / ST)               // 8 bins per thread
#define CAP HSIZE                      // collection buffer reuses hist LDS

// ---------------- match: per-gt best prior, object-parallel (1 wave = 1 (b,obj,chunk)) ----------------
__global__ __launch_bounds__(MTB) void k_match(const float* __restrict__ priors,
                                               const float* __restrict__ gt_boxes,
                                               unsigned long long* __restrict__ gkey) {
    const int wid = threadIdx.x >> 6, lane = threadIdx.x & 63;
    const int job = blockIdx.x * 4 + wid;        // 0..4095
    const int b = job >> 8;                      // 256 jobs per batch
    const int n = (job >> 3) & 31;
    const int c = job & 7;

    const float4 g = ((const float4*)gt_boxes)[b * NOBJ + n];   // wave-uniform
    float garea;
    {
#pragma clang fp contract(off)
        garea = (g.z - g.x) * (g.w - g.y);
    }

    unsigned long long bestkey = 0ull;
    const int pbeg = c * CHLEN;
    const int pend = pbeg + CHLEN;
    for (int p = pbeg + lane; p < pend; p += 64) {
        float4 pr = ((const float4*)priors)[p];
        float iou;
        {
#pragma clang fp contract(off)
            float hw = pr.z / 2.0f, hh = pr.w / 2.0f;
            float px1 = pr.x - hw, py1 = pr.y - hh, px2 = pr.x + hw, py2 = pr.y + hh;
            float parea = (px2 - px1) * (py2 - py1);
            float ix1 = fmaxf(g.x, px1), iy1 = fmaxf(g.y, py1);
            float ix2 = fminf(g.z, px2), iy2 = fminf(g.w, py2);
            float iw = fmaxf(ix2 - ix1, 0.0f), ih = fmaxf(iy2 - iy1, 0.0f);
            float inter = iw * ih;
            iou = inter / (garea + parea - inter);
        }
        // key: larger iou wins; tie -> smaller p (first-max, matches jnp.argmax axis=1)
        unsigned long long key = (((unsigned long long)__float_as_uint(iou)) << 32) |
                                 (unsigned long long)(0xFFFFFFFFu - (unsigned)p);
        if (key > bestkey) bestkey = key;
    }
#pragma unroll
    for (int m = 1; m < 64; m <<= 1) {
        unsigned long long o = __shfl_xor(bestkey, m, 64);
        if (o > bestkey) bestkey = o;
    }
    if (lane == 0) atomicMax(&gkey[b * NOBJ + n], bestkey);
}

// ---------------- prior: per-prior best gt -> packed (ti<<2 | cls); pure per-lane ----------------
__global__ __launch_bounds__(MTB) void k_prior(const float* __restrict__ priors,
                                               const float* __restrict__ gt_boxes,
                                               int* __restrict__ bp) {
    const int b = blockIdx.y;
    const int p = blockIdx.x * MTB + threadIdx.x;
    __shared__ float4 sg[NOBJ];
    if (threadIdx.x < NOBJ) sg[threadIdx.x] = ((const float4*)gt_boxes)[b * NOBJ + threadIdx.x];
    __syncthreads();
    if (p >= PP) return;

    float4 pr = ((const float4*)priors)[p];
    float px1, py1, px2, py2, parea;
    {
#pragma clang fp contract(off)
        float hw = pr.z / 2.0f, hh = pr.w / 2.0f;
        px1 = pr.x - hw; py1 = pr.y - hh; px2 = pr.x + hw; py2 = pr.y + hh;
        parea = (px2 - px1) * (py2 - py1);
    }

    float best = -1.0f;
    int bn = 0;
#pragma unroll 4
    for (int n = 0; n < NOBJ; ++n) {
        float4 g = sg[n];
        float iou;
        {
#pragma clang fp contract(off)
            float ix1 = fmaxf(g.x, px1), iy1 = fmaxf(g.y, py1);
            float ix2 = fminf(g.z, px2), iy2 = fminf(g.w, py2);
            float iw = fmaxf(ix2 - ix1, 0.0f), ih = fmaxf(iy2 - iy1, 0.0f);
            float inter = iw * ih;
            float garea = (g.z - g.x) * (g.w - g.y);
            iou = inter / (garea + parea - inter);
        }
        if (iou > best) { best = iou; bn = n; }   // strict > : first-max (argmax axis=0)
    }
    int cls = 2;                                  // positive
    if (best < POS_TH) cls = 1;                   // neutral
    if (best < NEG_TH) cls = 0;                   // background
    bp[(size_t)b * PP + p] = (bn << 2) | cls;
}

__device__ __forceinline__ float sl1(float d) {
    float ad = fabsf(d);
    return ad < 1.0f ? 0.5f * d * d : ad - 0.5f;
}

// ---------------- main: 16-lane LSE; zero dependent loads on common path; per-wave slots ----------------
// wave = 4 rows (16 lanes each); block = 16 waves = 64 rows; NO __syncthreads, NO LDS.
__global__ __launch_bounds__(MAINB) void k_main(const float* __restrict__ loc_data,
                                                const float* __restrict__ conf_data,
                                                const float* __restrict__ priors,
                                                const float* __restrict__ gt_boxes,
                                                const int* __restrict__ gt_labels,
                                                const int* __restrict__ bp,
                                                const unsigned long long* __restrict__ gkey,
                                                float* __restrict__ mine,
                                                float* __restrict__ p_ll,
                                                float* __restrict__ p_lc,
                                                int* __restrict__ p_np) {
    const int b = blockIdx.y;
    const int t = threadIdx.x;
    const int wid = t >> 6;            // 0..15
    const int lane = t & 63;
    const int g = lane >> 4;           // row-group within wave: 0..3
    const int j = lane & 15;           // lane within row-group
    const int rbase = blockIdx.x * ROWS_PB + wid * 4;
    const int r = rbase + g;           // wave-uniform validity: PP % 4 == 0
    const bool valid = r < PP;
    const int slot = blockIdx.x * 16 + wid;

    // lanes 0..31: forced-prior index + label for object `lane` (batch-wide metadata in regs)
    unsigned pst = 0xFFFFFFFFu;
    int labreg = 0;
    if (lane < NOBJ) {
        pst = 0xFFFFFFFFu - (unsigned)(gkey[b * NOBJ + lane] & 0xFFFFFFFFull);
        labreg = gt_labels[b * NOBJ + lane];
    }

    // independent loads issued together: 5 conf dwords + packed match word (broadcast per group)
    const float* rowp = conf_data + ((size_t)b * PP + r) * NCLS;
    float c0 = 0.f, c1 = 0.f, c2 = 0.f, c3 = 0.f, c4 = 0.f, c80 = 0.f;
    int packed = 0;
    if (valid) {
        c0 = rowp[j];
        c1 = rowp[j + 16];
        c2 = rowp[j + 32];
        c3 = rowp[j + 48];
        c4 = rowp[j + 64];
        if (j == 0) c80 = rowp[80];
        packed = bp[(size_t)b * PP + r];
    }

    // parallel logsumexp across the 16-lane group
    float s = __expf(c0) + __expf(c1) + __expf(c2) + __expf(c3) + __expf(c4);
    if (j == 0) s += __expf(c80);
    s += __shfl_xor(s, 1, 64);
    s += __shfl_xor(s, 2, 64);
    s += __shfl_xor(s, 4, 64);
    s += __shfl_xor(s, 8, 64);
    const float lse = __logf(s);

    // forced-positive: one ballot per row; last-wins = highest set bit (largest object idx)
    unsigned long long b0 = __ballot(pst == (unsigned)(rbase + 0));
    unsigned long long b1 = __ballot(pst == (unsigned)(rbase + 1));
    unsigned long long b2 = __ballot(pst == (unsigned)(rbase + 2));
    unsigned long long b3 = __ballot(pst == (unsigned)(rbase + 3));
    unsigned long long mball = (g == 0) ? b0 : (g == 1) ? b1 : (g == 2) ? b2 : b3;

    int ti = packed >> 2;
    int cls = packed & 3;
    if (mball) { ti = 63 - __builtin_clzll(mball); cls = 2; }

    // label via register shuffle (no dependent global load)
    const int lab = __shfl(labreg, ti, 64);
    int conf_c = (cls == 2) ? (lab + 1) : ((cls == 1) ? -1 : 0);

    // row[0] is already in lane (group_base).c0 — no load for the negative-row nll
    const float row0 = __shfl(c0, lane & 48, 64);
    const float nll0 = lse - row0;

    float my_ll = 0.0f, my_lc = 0.0f;
    int my_pos = 0;

    if (valid && j == 0) {
        mine[(size_t)b * PP + r] = (conf_c == 0) ? nll0 : 0.0f;
        if (conf_c > 0) {           // rare branch: positives only
            my_pos = 1;
            my_lc = lse - rowp[conf_c];
            float4 gbox = ((const float4*)gt_boxes)[b * NOBJ + ti];
            float4 pr = ((const float4*)priors)[r];
            float mcx = (gbox.x + gbox.z) / 2.0f, mcy = (gbox.y + gbox.w) / 2.0f;
            float mw = gbox.z - gbox.x, mh = gbox.w - gbox.y;
            float t0 = (mcx - pr.x) / (VAR0 * pr.z);
            float t1 = (mcy - pr.y) / (VAR0 * pr.w);
            float t2 = logf(mw / pr.z) / VAR1;
            float t3 = logf(mh / pr.w) / VAR1;
            float4 ld = ((const float4*)loc_data)[(size_t)b * PP + r];
            my_ll = sl1(ld.x - t0) + sl1(ld.y - t1) + sl1(ld.z - t2) + sl1(ld.w - t3);
        }
    }

    // per-wave slot store; skip the whole reduce when the wave has no positives (~99%)
    if (__ballot(my_pos != 0) == 0ull) {
        if (lane == 0) {
            p_ll[b * NSLOTW + slot] = 0.0f;
            p_lc[b * NSLOTW + slot] = 0.0f;
            p_np[b * NSLOTW + slot] = 0;
        }
    } else {
        for (int off = 32; off > 0; off >>= 1) {
            my_ll += __shfl_down(my_ll, off, 64);
            my_lc += __shfl_down(my_lc, off, 64);
            my_pos += __shfl_down(my_pos, off, 64);
        }
        if (lane == 0) {
            p_ll[b * NSLOTW + slot] = my_ll;
            p_lc[b * NSLOTW + slot] = my_lc;
            p_np[b * NSLOTW + slot] = my_pos;
        }
    }
}

// ---------------- select: histogram top-k (2 global scans) + LDS refine + fused finalize ----------------
__global__ __launch_bounds__(ST) void k_select(const float* __restrict__ mine,
                                               const float* __restrict__ p_ll,
                                               const float* __restrict__ p_lc,
                                               const int* __restrict__ p_np,
                                               float* __restrict__ acc,
                                               int* __restrict__ acc_np,
                                               unsigned* __restrict__ done,
                                               float* __restrict__ out) {
    const int b = blockIdx.x;
    const int tid = threadIdx.x;
    const int wid = tid >> 6, lane = tid & 63;
    constexpr int NW = ST / 64;

    __shared__ unsigned hist[HSIZE];           // 32 KB; reused as collection buffer
    __shared__ unsigned s_tsum[ST];            // 4 KB
    __shared__ unsigned s_wsum[NW];
    __shared__ float rll[NW], rlc[NW];
    __shared__ int rnp[NW];
    __shared__ float rs1[NW], rs2[NW];
    __shared__ unsigned rc2[NW];
    __shared__ float s_ll, s_lc, s_neg;
    __shared__ int s_np, s_B, s_G1;
    __shared__ unsigned s_cntB, s_cnt, s_prefix;
    __shared__ int s_rem;
    __shared__ unsigned h16[16];
    // fallback radix shared state
    __shared__ unsigned swh[NW * 16];
    __shared__ unsigned stot[16];

    // ---- 1. reduce this batch's partial slots ----
    float ll = 0.0f, lc = 0.0f;
    int np = 0;
    for (int i = tid; i < NSLOTW; i += ST) {
        ll += p_ll[b * NSLOTW + i];
        lc += p_lc[b * NSLOTW + i];
        np += p_np[b * NSLOTW + i];
    }
    for (int off = 32; off > 0; off >>= 1) {
        ll += __shfl_down(ll, off, 64);
        lc += __shfl_down(lc, off, 64);
        np += __shfl_down(np, off, 64);
    }
    if (lane == 0) { rll[wid] = ll; rlc[wid] = lc; rnp[wid] = np; }
    __syncthreads();
    if (tid == 0) {
        float a = 0.0f, c = 0.0f;
        int n = 0;
        for (int w = 0; w < NW; ++w) { a += rll[w]; c += rlc[w]; n += rnp[w]; }
        s_ll = a; s_lc = c; s_np = n;
        s_neg = 0.0f;
    }
    __syncthreads();
    const int np_b = s_np;
    const int k = min(NEGPOS * np_b, PP - 1);

    const float* mv = mine + (size_t)b * PP;
    const float4* mv4 = (const float4*)mv;
    constexpr int PP4 = PP / 4;   // 4812

    if (k > 0) {
        // ---- 2. scan 1: 8192-bin LDS histogram of bits>>19 (float4 loads, pipelined) ----
        for (int i = tid; i < HSIZE; i += ST) hist[i] = 0u;
        __syncthreads();
        for (int i = tid; i < PP4; i += ST) {
            float4 v = mv4[i];
            atomicAdd(&hist[__float_as_uint(v.x) >> HSHIFT], 1u);
            atomicAdd(&hist[__float_as_uint(v.y) >> HSHIFT], 1u);
            atomicAdd(&hist[__float_as_uint(v.z) >> HSHIFT], 1u);
            atomicAdd(&hist[__float_as_uint(v.w) >> HSHIFT], 1u);
        }
        __syncthreads();

        // ---- 3. find boundary bin B (suffix scan from top: waves -> threads -> bins) ----
        unsigned tsum = 0;
        const int hb = tid * HPT;
#pragma unroll
        for (int v = 0; v < HPT; ++v) tsum += hist[hb + v];
        s_tsum[tid] = tsum;
        unsigned wsum = tsum;
        for (int off = 32; off > 0; off >>= 1) wsum += __shfl_down(wsum, off, 64);
        if (lane == 0) s_wsum[wid] = wsum;
        __syncthreads();
        if (tid == 0) {
            unsigned cum = 0;
            int w = NW - 1;
            for (; w > 0; --w) {
                if (cum + s_wsum[w] >= (unsigned)k) break;
                cum += s_wsum[w];
            }
            int t = (w + 1) * 64 - 1;
            for (; t > w * 64; --t) {
                if (cum + s_tsum[t] >= (unsigned)k) break;
                cum += s_tsum[t];
            }
            int bin = t * HPT + HPT - 1;
            for (; bin > t * HPT; --bin) {
                if (cum + hist[bin] >= (unsigned)k) break;
                cum += hist[bin];
            }
            s_B = bin;
            s_G1 = (int)cum;          // count strictly above bin B
            s_cntB = hist[bin];
            s_cnt = 0u;
        }
        __syncthreads();
        const int B = s_B;
        const int r = k - s_G1;                         // 1 <= r <= cntB
        const unsigned cntB = s_cntB;
        const unsigned bin_lo = (unsigned)B << HSHIFT;
        const unsigned hi_base = (unsigned)(B + 1) << HSHIFT;
        unsigned* cbuf = hist;                          // reuse (all hist reads are done)

        if (cntB <= CAP) {
            // ---- 4. scan 2: exact sum above bin B + collect bin-B elements into LDS ----
            float S1 = 0.0f;
            for (int i = tid; i < PP4; i += ST) {
                float4 v = mv4[i];
                unsigned bx = __float_as_uint(v.x);
                unsigned by = __float_as_uint(v.y);
                unsigned bz = __float_as_uint(v.z);
                unsigned bw = __float_as_uint(v.w);
                if (bx >= hi_base) S1 += v.x;
                else if (bx >= bin_lo) cbuf[atomicAdd(&s_cnt, 1u)] = bx;
                if (by >= hi_base) S1 += v.y;
                else if (by >= bin_lo) cbuf[atomicAdd(&s_cnt, 1u)] = by;
                if (bz >= hi_base) S1 += v.z;
                else if (bz >= bin_lo) cbuf[atomicAdd(&s_cnt, 1u)] = bz;
                if (bw >= hi_base) S1 += v.w;
                else if (bw >= bin_lo) cbuf[atomicAdd(&s_cnt, 1u)] = bw;
            }
            for (int off = 32; off > 0; off >>= 1) S1 += __shfl_down(S1, off, 64);
            if (lane == 0) rs1[wid] = S1;
            __syncthreads();   // also fences the collection writes

            // ---- 5. refine low 19 bits among the cntB collected elements (LDS-resident) ----
            if (tid == 0) { s_prefix = bin_lo; s_rem = r; }
            __syncthreads();
            for (int pass = 0; pass < 5; ++pass) {
                const int shift = (pass < 4) ? (15 - 4 * pass) : 0;
                const int width = (pass < 4) ? 4 : 3;
                const int nb = 1 << width;
                const unsigned hm = 0xFFFFFFFFu << (shift + width);
                if (tid < 16) h16[tid] = 0u;
                __syncthreads();
                const unsigned prefix = s_prefix;
                for (unsigned i = tid; i < cntB; i += ST) {
                    unsigned bits = cbuf[i];
                    if ((bits & hm) == prefix)
                        atomicAdd(&h16[(bits >> shift) & (nb - 1)], 1u);
                }
                __syncthreads();
                if (tid == 0) {
                    int rem = s_rem;
                    unsigned cum = 0;
                    int chosen = 0;
                    for (int v = nb - 1; v >= 0; --v) {
                        unsigned c = h16[v];
                        if (cum + c >= (unsigned)rem) { chosen = v; s_rem = rem - (int)cum; break; }
                        cum += c;
                    }
                    s_prefix = prefix | ((unsigned)chosen << shift);
                }
                __syncthreads();
            }
            const unsigned T = s_prefix;   // exact bits of the r-th largest within bin B

            // ---- 6. final: sum collected > T, tie-fill with T ----
            float S2 = 0.0f;
            unsigned c2 = 0;
            for (unsigned i = tid; i < cntB; i += ST) {
                unsigned bits = cbuf[i];
                if (bits > T) { S2 += __uint_as_float(bits); c2++; }
            }
            for (int off = 32; off > 0; off >>= 1) {
                S2 += __shfl_down(S2, off, 64);
                c2 += __shfl_down(c2, off, 64);
            }
            if (lane == 0) { rs2[wid] = S2; rc2[wid] = c2; }
            __syncthreads();
            if (tid == 0) {
                float S1t = 0.0f, S2t = 0.0f;
                unsigned c2t = 0;
                for (int w = 0; w < NW; ++w) { S1t += rs1[w]; S2t += rs2[w]; c2t += rc2[w]; }
                s_neg = S1t + S2t + (float)(r - (int)c2t) * __uint_as_float(T);
            }
            __syncthreads();
        } else {
            // ---- fallback (collection overflow — practically unreachable): 8-pass global radix ----
            if (tid == 0) { s_prefix = 0u; s_rem = k; }
            __syncthreads();
            for (int pass = 0; pass < 8; ++pass) {
                const int shift = 28 - 4 * pass;
                const unsigned hm = (pass == 0) ? 0u : (0xFFFFFFFFu << (shift + 4));
                const unsigned prefix = s_prefix;
                unsigned cnt[16];
#pragma unroll
                for (int v = 0; v < 16; ++v) cnt[v] = 0u;
                for (int i = tid; i < PP; i += ST) {
                    unsigned bits = __float_as_uint(mv[i]);
                    unsigned key = ((bits & hm) == prefix) ? ((bits >> shift) & 15u) : 16u;
                    if (__any(key != 16u)) {
#pragma unroll
                        for (int v = 0; v < 16; ++v)
                            cnt[v] += (unsigned)__popcll(__ballot(key == (unsigned)v));
                    }
                }
                if (lane == 0) {
#pragma unroll
                    for (int v = 0; v < 16; ++v) swh[wid * 16 + v] = cnt[v];
                }
                __syncthreads();
                if (tid < 16) {
                    unsigned tt = 0;
#pragma unroll
                    for (int w = 0; w < NW; ++w) tt += swh[w * 16 + tid];
                    stot[tid] = tt;
                }
                __syncthreads();
                if (tid == 0) {
                    int rem = s_rem;
                    unsigned cum = 0;
                    int chosen = 0;
                    for (int v = 15; v >= 0; --v) {
                        unsigned c = stot[v];
                        if (cum + c >= (unsigned)rem) { chosen = v; s_rem = rem - (int)cum; break; }
                        cum += c;
                    }
                    s_prefix = prefix | ((unsigned)chosen << shift);
                }
                __syncthreads();
            }
            const unsigned T = s_prefix;
            float sum = 0.0f;
            unsigned cnt = 0;
            for (int i = tid; i < PP; i += ST) {
                float v = mv[i];
                if (__float_as_uint(v) > T) { sum += v; cnt++; }
            }
            for (int off = 32; off > 0; off >>= 1) {
                sum += __shfl_down(sum, off, 64);
                cnt += __shfl_down(cnt, off, 64);
            }
            if (lane == 0) { rs2[wid] = sum; rc2[wid] = cnt; }
            __syncthreads();
            if (tid == 0) {
                float S = 0.0f;
                int G = 0;
                for (int w = 0; w < NW; ++w) { S += rs2[w]; G += (int)rc2[w]; }
                s_neg = S + (float)(k - G) * __uint_as_float(T);
            }
            __syncthreads();
        }
    }

    if (tid == 0) {
        atomicAdd(&acc[0], s_ll);
        atomicAdd(&acc[1], s_lc + s_neg);
        atomicAdd(acc_np, np_b);
        __threadfence();
        unsigned prev = atomicAdd(done, 1u);
        if (prev == BB - 1) {
            int tp = atomicAdd(acc_np, 0);
            float N = (float)max(tp, 1);
            float a0 = atomicAdd(&acc[0], 0.0f);
            float a1 = atomicAdd(&acc[1], 0.0f);
            out[0] = a0 / N;
            out[1] = a1 / N;
        }
    }
}

extern "C" void kernel_launch(void* const* d_in, const int* in_sizes, int n_in,
                              void* d_out, int out_size, void* d_ws, size_t ws_size,
                              hipStream_t stream) {
    const float* loc    = (const float*)d_in[0];
    const float* conf   = (const float*)d_in[1];
    const float* priors = (const float*)d_in[2];
    const float* gt     = (const float*)d_in[3];
    const int*   labels = (const int*)d_in[4];
    float* out = (float*)d_out;

    char* ws = (char*)d_ws;
    const size_t SZ_BP = (size_t)BB * PP * 4;          // 1,231,872 B
    const size_t SZ_SLOT = (size_t)BB * NSLOTW * 4;    // 308,224 B
    // [0,4096) gkey | [4096,4104) acc | [4104,4108) acc_np | [4108,4112) done | pad 4224
    unsigned long long* gkey = (unsigned long long*)ws;
    float*    acc    = (float*)   (ws + 4096);
    int*      acc_np = (int*)     (ws + 4104);
    unsigned* done   = (unsigned*)(ws + 4108);
    int*   bp   = (int*)  (ws + 4224);
    float* mine = (float*)(ws + 4224 + SZ_BP);
    float* p_ll = (float*)(ws + 4224 + 2 * SZ_BP);
    float* p_lc = (float*)(ws + 4224 + 2 * SZ_BP + SZ_SLOT);
    int*   p_np = (int*)  (ws + 4224 + 2 * SZ_BP + 2 * SZ_SLOT);

    (void)hipMemsetAsync(ws, 0, 4224, stream);   // gkey + acc + acc_np + done

    k_match<<<MBLK, MTB, 0, stream>>>(priors, gt, gkey);

    dim3 pg(NMB, BB);
    k_prior<<<pg, MTB, 0, stream>>>(priors, gt, bp);

    dim3 kg(NSLOT, BB);
    k_main<<<kg, MAINB, 0, stream>>>(loc, conf, priors, gt, labels, bp, gkey,
                                     mine, p_ll, p_lc, p_np);

    k_select<<<BB, ST, 0, stream>>>(mine, p_ll, p_lc, p_np, acc, acc_np, done, out);
}

// Round 5
// 210.851 us; speedup vs baseline: 1.0303x; 1.0130x over previous
//
#include <hip/hip_runtime.h>
#include <cstdint>
#include <cstddef>

#define BB 16
#define PP 19248
#define NOBJ 32
#define NCLS 81
#define POS_TH 0.5f
#define NEG_TH 0.4f
#define VAR0 0.1f
#define VAR1 0.2f
#define NEGPOS 3

#define MTB 256
#define NMB ((PP + MTB - 1) / MTB)    // 76
#define MAINB 1024
#define ROWS_PB 128                    // rows per k_main block (8 rows/wave * 16 waves)
#define NSLOT ((PP + ROWS_PB - 1) / ROWS_PB)   // 151 blocks/batch
#define NSLOTW (NSLOT * 16)            // 2416 per-wave slots/batch
#define ST 1024

// object-parallel match parameters
#define MCH 8                          // prior chunks per object
#define CHLEN (PP / MCH)               // 2406 (exact)
#define MJOBS (BB * NOBJ * MCH)        // 4096 wave-jobs
#define MBLK (MJOBS / 4)               // 1024 blocks of 4 waves

// histogram select parameters
#define HSHIFT 19
#define HSIZE 8192                     // bins = bits >> 19 (13 bits)
#define HPT (HSIZE / ST)               // 8 bins per thread
#define CAP HSIZE                      // collection buffer reuses hist LDS

// ---------------- match: per-gt best prior, object-parallel (1 wave = 1 (b,obj,chunk)) ----------------
__global__ __launch_bounds__(MTB) void k_match(const float* __restrict__ priors,
                                               const float* __restrict__ gt_boxes,
                                               unsigned long long* __restrict__ gkey) {
    const int wid = threadIdx.x >> 6, lane = threadIdx.x & 63;
    const int job = blockIdx.x * 4 + wid;        // 0..4095
    const int b = job >> 8;                      // 256 jobs per batch
    const int n = (job >> 3) & 31;
    const int c = job & 7;

    const float4 g = ((const float4*)gt_boxes)[b * NOBJ + n];   // wave-uniform
    float garea;
    {
#pragma clang fp contract(off)
        garea = (g.z - g.x) * (g.w - g.y);
    }

    unsigned long long bestkey = 0ull;
    const int pbeg = c * CHLEN;
    const int pend = pbeg + CHLEN;
    for (int p = pbeg + lane; p < pend; p += 64) {
        float4 pr = ((const float4*)priors)[p];
        float iou;
        {
#pragma clang fp contract(off)
            float hw = pr.z / 2.0f, hh = pr.w / 2.0f;
            float px1 = pr.x - hw, py1 = pr.y - hh, px2 = pr.x + hw, py2 = pr.y + hh;
            float parea = (px2 - px1) * (py2 - py1);
            float ix1 = fmaxf(g.x, px1), iy1 = fmaxf(g.y, py1);
            float ix2 = fminf(g.z, px2), iy2 = fminf(g.w, py2);
            float iw = fmaxf(ix2 - ix1, 0.0f), ih = fmaxf(iy2 - iy1, 0.0f);
            float inter = iw * ih;
            iou = inter / (garea + parea - inter);
        }
        // key: larger iou wins; tie -> smaller p (first-max, matches jnp.argmax axis=1)
        unsigned long long key = (((unsigned long long)__float_as_uint(iou)) << 32) |
                                 (unsigned long long)(0xFFFFFFFFu - (unsigned)p);
        if (key > bestkey) bestkey = key;
    }
#pragma unroll
    for (int m = 1; m < 64; m <<= 1) {
        unsigned long long o = __shfl_xor(bestkey, m, 64);
        if (o > bestkey) bestkey = o;
    }
    if (lane == 0) atomicMax(&gkey[b * NOBJ + n], bestkey);
}

// ---------------- prior: per-prior best gt -> packed (ti<<8 | conf_c+1), labels folded in ----------------
__global__ __launch_bounds__(MTB) void k_prior(const float* __restrict__ priors,
                                               const float* __restrict__ gt_boxes,
                                               const int* __restrict__ gt_labels,
                                               unsigned* __restrict__ bp) {
    const int b = blockIdx.y;
    const int p = blockIdx.x * MTB + threadIdx.x;
    __shared__ float4 sg[NOBJ];
    __shared__ int slab[NOBJ];
    if (threadIdx.x < NOBJ) {
        sg[threadIdx.x] = ((const float4*)gt_boxes)[b * NOBJ + threadIdx.x];
        slab[threadIdx.x] = gt_labels[b * NOBJ + threadIdx.x];
    }
    __syncthreads();
    if (p >= PP) return;

    float4 pr = ((const float4*)priors)[p];
    float px1, py1, px2, py2, parea;
    {
#pragma clang fp contract(off)
        float hw = pr.z / 2.0f, hh = pr.w / 2.0f;
        px1 = pr.x - hw; py1 = pr.y - hh; px2 = pr.x + hw; py2 = pr.y + hh;
        parea = (px2 - px1) * (py2 - py1);
    }

    float best = -1.0f;
    int bn = 0;
#pragma unroll 4
    for (int n = 0; n < NOBJ; ++n) {
        float4 g = sg[n];
        float iou;
        {
#pragma clang fp contract(off)
            float ix1 = fmaxf(g.x, px1), iy1 = fmaxf(g.y, py1);
            float ix2 = fminf(g.z, px2), iy2 = fminf(g.w, py2);
            float iw = fmaxf(ix2 - ix1, 0.0f), ih = fmaxf(iy2 - iy1, 0.0f);
            float inter = iw * ih;
            float garea = (g.z - g.x) * (g.w - g.y);
            iou = inter / (garea + parea - inter);
        }
        if (iou > best) { best = iou; bn = n; }   // strict > : first-max (argmax axis=0)
    }
    // cc = conf_c + 1: neutral->0, background->1, positive->lab+2
    unsigned cc;
    if (best < NEG_TH) cc = 1u;
    else if (best < POS_TH) cc = 0u;
    else cc = (unsigned)(slab[bn] + 2);
    bp[(size_t)b * PP + p] = ((unsigned)bn << 8) | cc;
}

// ---------------- force: patch the <=512 forced rows; bit31 wins, higher n = last-wins ----------------
__global__ __launch_bounds__(512) void k_force(const int* __restrict__ gt_labels,
                                               const unsigned long long* __restrict__ gkey,
                                               unsigned* __restrict__ bp) {
    const int i = threadIdx.x;          // 0..511
    const int b = i >> 5, n = i & 31;
    unsigned long long key = gkey[b * NOBJ + n];
    unsigned pstar = 0xFFFFFFFFu - (unsigned)(key & 0xFFFFFFFFull);
    int lab = gt_labels[b * NOBJ + n];
    unsigned val = 0x80000000u | ((unsigned)n << 8) | (unsigned)(lab + 2);
    atomicMax(&bp[(size_t)b * PP + pstar], val);
}

__device__ __forceinline__ float sl1(float d) {
    float ad = fabsf(d);
    return ad < 1.0f ? 0.5f * d * d : ad - 0.5f;
}

// ---------------- main: 8-lane LSE, 8 rows/wave; zero metadata work, per-wave slots ----------------
// wave = 8 rows (8 lanes each); block = 16 waves = 128 rows; NO __syncthreads, NO LDS.
__global__ __launch_bounds__(MAINB) void k_main(const float* __restrict__ loc_data,
                                                const float* __restrict__ conf_data,
                                                const float* __restrict__ priors,
                                                const float* __restrict__ gt_boxes,
                                                const unsigned* __restrict__ bp,
                                                float* __restrict__ mine,
                                                float* __restrict__ p_ll,
                                                float* __restrict__ p_lc,
                                                int* __restrict__ p_np) {
    const int b = blockIdx.y;
    const int t = threadIdx.x;
    const int wid = t >> 6;            // 0..15
    const int lane = t & 63;
    const int g = lane >> 3;           // row-group within wave: 0..7
    const int j = lane & 7;            // lane within row-group
    const int rbase = blockIdx.x * ROWS_PB + wid * 8;
    const int r = rbase + g;           // wave-uniform validity: PP % 8 == 0
    const bool valid = r < PP;
    const int slot = blockIdx.x * 16 + wid;

    // loads: 10 conf dwords (classes j, j+8, ..., j+72), c80 on j==0, packed match word
    const float* rowp = conf_data + ((size_t)b * PP + r) * NCLS;
    float c[10];
#pragma unroll
    for (int i = 0; i < 10; ++i) c[i] = 0.0f;
    float c80 = 0.0f;
    unsigned w = 1u;                   // background for invalid lanes (harmless)
    if (valid) {
#pragma unroll
        for (int i = 0; i < 10; ++i) c[i] = rowp[j + 8 * i];
        if (j == 0) c80 = rowp[80];
        w = bp[(size_t)b * PP + r];
    }

    // parallel logsumexp across the 8-lane group
    float s = 0.0f;
#pragma unroll
    for (int i = 0; i < 10; ++i) s += __expf(c[i]);
    if (j == 0) s += __expf(c80);
    s += __shfl_xor(s, 1, 64);
    s += __shfl_xor(s, 2, 64);
    s += __shfl_xor(s, 4, 64);
    const float lse = __logf(s);

    const int cc = (int)(w & 0xFFu);   // 0 neutral, 1 background, >=2 positive (lab+2)

    float my_ll = 0.0f, my_lc = 0.0f;
    int my_pos = 0;

    if (valid && j == 0) {
        // background nll uses this lane's own c[0] (= row[0]); no extra load
        mine[(size_t)b * PP + r] = (cc == 1) ? (lse - c[0]) : 0.0f;
        if (cc >= 2) {                 // rare branch: positives only
            my_pos = 1;
            my_lc = lse - rowp[cc - 1];
            const int ti = (int)((w >> 8) & 63u);
            float4 gbox = ((const float4*)gt_boxes)[b * NOBJ + ti];
            float4 pr = ((const float4*)priors)[r];
            float mcx = (gbox.x + gbox.z) / 2.0f, mcy = (gbox.y + gbox.w) / 2.0f;
            float mw = gbox.z - gbox.x, mh = gbox.w - gbox.y;
            float t0 = (mcx - pr.x) / (VAR0 * pr.z);
            float t1 = (mcy - pr.y) / (VAR0 * pr.w);
            float t2 = logf(mw / pr.z) / VAR1;
            float t3 = logf(mh / pr.w) / VAR1;
            float4 ld = ((const float4*)loc_data)[(size_t)b * PP + r];
            my_ll = sl1(ld.x - t0) + sl1(ld.y - t1) + sl1(ld.z - t2) + sl1(ld.w - t3);
        }
    }

    // per-wave slot store; skip the reduce when the wave has no positives (~99%)
    if (__ballot(my_pos != 0) == 0ull) {
        if (lane == 0) {
            p_ll[b * NSLOTW + slot] = 0.0f;
            p_lc[b * NSLOTW + slot] = 0.0f;
            p_np[b * NSLOTW + slot] = 0;
        }
    } else {
        for (int off = 32; off > 0; off >>= 1) {
            my_ll += __shfl_down(my_ll, off, 64);
            my_lc += __shfl_down(my_lc, off, 64);
            my_pos += __shfl_down(my_pos, off, 64);
        }
        if (lane == 0) {
            p_ll[b * NSLOTW + slot] = my_ll;
            p_lc[b * NSLOTW + slot] = my_lc;
            p_np[b * NSLOTW + slot] = my_pos;
        }
    }
}

// ---------------- select: histogram top-k (2 global scans) + LDS refine + fused finalize ----------------
__global__ __launch_bounds__(ST) void k_select(const float* __restrict__ mine,
                                               const float* __restrict__ p_ll,
                                               const float* __restrict__ p_lc,
                                               const int* __restrict__ p_np,
                                               float* __restrict__ acc,
                                               int* __restrict__ acc_np,
                                               unsigned* __restrict__ done,
                                               float* __restrict__ out) {
    const int b = blockIdx.x;
    const int tid = threadIdx.x;
    const int wid = tid >> 6, lane = tid & 63;
    constexpr int NW = ST / 64;

    __shared__ unsigned hist[HSIZE];           // 32 KB; reused as collection buffer
    __shared__ unsigned s_tsum[ST];            // 4 KB
    __shared__ unsigned s_wsum[NW];
    __shared__ float rll[NW], rlc[NW];
    __shared__ int rnp[NW];
    __shared__ float rs1[NW], rs2[NW];
    __shared__ unsigned rc2[NW];
    __shared__ float s_ll, s_lc, s_neg;
    __shared__ int s_np, s_B, s_G1;
    __shared__ unsigned s_cntB, s_cnt, s_prefix;
    __shared__ int s_rem;
    __shared__ unsigned h16[16];
    // fallback radix shared state
    __shared__ unsigned swh[NW * 16];
    __shared__ unsigned stot[16];

    // ---- 1. reduce this batch's partial slots ----
    float ll = 0.0f, lc = 0.0f;
    int np = 0;
    for (int i = tid; i < NSLOTW; i += ST) {
        ll += p_ll[b * NSLOTW + i];
        lc += p_lc[b * NSLOTW + i];
        np += p_np[b * NSLOTW + i];
    }
    for (int off = 32; off > 0; off >>= 1) {
        ll += __shfl_down(ll, off, 64);
        lc += __shfl_down(lc, off, 64);
        np += __shfl_down(np, off, 64);
    }
    if (lane == 0) { rll[wid] = ll; rlc[wid] = lc; rnp[wid] = np; }
    __syncthreads();
    if (tid == 0) {
        float a = 0.0f, c = 0.0f;
        int n = 0;
        for (int w = 0; w < NW; ++w) { a += rll[w]; c += rlc[w]; n += rnp[w]; }
        s_ll = a; s_lc = c; s_np = n;
        s_neg = 0.0f;
    }
    __syncthreads();
    const int np_b = s_np;
    const int k = min(NEGPOS * np_b, PP - 1);

    const float* mv = mine + (size_t)b * PP;
    const float4* mv4 = (const float4*)mv;
    constexpr int PP4 = PP / 4;   // 4812

    if (k > 0) {
        // ---- 2. scan 1: 8192-bin LDS histogram of bits>>19 (float4 loads, pipelined) ----
        for (int i = tid; i < HSIZE; i += ST) hist[i] = 0u;
        __syncthreads();
        for (int i = tid; i < PP4; i += ST) {
            float4 v = mv4[i];
            atomicAdd(&hist[__float_as_uint(v.x) >> HSHIFT], 1u);
            atomicAdd(&hist[__float_as_uint(v.y) >> HSHIFT], 1u);
            atomicAdd(&hist[__float_as_uint(v.z) >> HSHIFT], 1u);
            atomicAdd(&hist[__float_as_uint(v.w) >> HSHIFT], 1u);
        }
        __syncthreads();

        // ---- 3. find boundary bin B (suffix scan from top: waves -> threads -> bins) ----
        unsigned tsum = 0;
        const int hb = tid * HPT;
#pragma unroll
        for (int v = 0; v < HPT; ++v) tsum += hist[hb + v];
        s_tsum[tid] = tsum;
        unsigned wsum = tsum;
        for (int off = 32; off > 0; off >>= 1) wsum += __shfl_down(wsum, off, 64);
        if (lane == 0) s_wsum[wid] = wsum;
        __syncthreads();
        if (tid == 0) {
            unsigned cum = 0;
            int w = NW - 1;
            for (; w > 0; --w) {
                if (cum + s_wsum[w] >= (unsigned)k) break;
                cum += s_wsum[w];
            }
            int t = (w + 1) * 64 - 1;
            for (; t > w * 64; --t) {
                if (cum + s_tsum[t] >= (unsigned)k) break;
                cum += s_tsum[t];
            }
            int bin = t * HPT + HPT - 1;
            for (; bin > t * HPT; --bin) {
                if (cum + hist[bin] >= (unsigned)k) break;
                cum += hist[bin];
            }
            s_B = bin;
            s_G1 = (int)cum;          // count strictly above bin B
            s_cntB = hist[bin];
            s_cnt = 0u;
        }
        __syncthreads();
        const int B = s_B;
        const int r = k - s_G1;                         // 1 <= r <= cntB
        const unsigned cntB = s_cntB;
        const unsigned bin_lo = (unsigned)B << HSHIFT;
        const unsigned hi_base = (unsigned)(B + 1) << HSHIFT;
        unsigned* cbuf = hist;                          // reuse (all hist reads are done)

        if (cntB <= CAP) {
            // ---- 4. scan 2: exact sum above bin B + collect bin-B elements into LDS ----
            float S1 = 0.0f;
            for (int i = tid; i < PP4; i += ST) {
                float4 v = mv4[i];
                unsigned bx = __float_as_uint(v.x);
                unsigned by = __float_as_uint(v.y);
                unsigned bz = __float_as_uint(v.z);
                unsigned bw = __float_as_uint(v.w);
                if (bx >= hi_base) S1 += v.x;
                else if (bx >= bin_lo) cbuf[atomicAdd(&s_cnt, 1u)] = bx;
                if (by >= hi_base) S1 += v.y;
                else if (by >= bin_lo) cbuf[atomicAdd(&s_cnt, 1u)] = by;
                if (bz >= hi_base) S1 += v.z;
                else if (bz >= bin_lo) cbuf[atomicAdd(&s_cnt, 1u)] = bz;
                if (bw >= hi_base) S1 += v.w;
                else if (bw >= bin_lo) cbuf[atomicAdd(&s_cnt, 1u)] = bw;
            }
            for (int off = 32; off > 0; off >>= 1) S1 += __shfl_down(S1, off, 64);
            if (lane == 0) rs1[wid] = S1;
            __syncthreads();   // also fences the collection writes

            // ---- 5. refine low 19 bits among the cntB collected elements (LDS-resident) ----
            if (tid == 0) { s_prefix = bin_lo; s_rem = r; }
            __syncthreads();
            for (int pass = 0; pass < 5; ++pass) {
                const int shift = (pass < 4) ? (15 - 4 * pass) : 0;
                const int width = (pass < 4) ? 4 : 3;
                const int nb = 1 << width;
                const unsigned hm = 0xFFFFFFFFu << (shift + width);
                if (tid < 16) h16[tid] = 0u;
                __syncthreads();
                const unsigned prefix = s_prefix;
                for (unsigned i = tid; i < cntB; i += ST) {
                    unsigned bits = cbuf[i];
                    if ((bits & hm) == prefix)
                        atomicAdd(&h16[(bits >> shift) & (nb - 1)], 1u);
                }
                __syncthreads();
                if (tid == 0) {
                    int rem = s_rem;
                    unsigned cum = 0;
                    int chosen = 0;
                    for (int v = nb - 1; v >= 0; --v) {
                        unsigned c = h16[v];
                        if (cum + c >= (unsigned)rem) { chosen = v; s_rem = rem - (int)cum; break; }
                        cum += c;
                    }
                    s_prefix = prefix | ((unsigned)chosen << shift);
                }
                __syncthreads();
            }
            const unsigned T = s_prefix;   // exact bits of the r-th largest within bin B

            // ---- 6. final: sum collected > T, tie-fill with T ----
            float S2 = 0.0f;
            unsigned c2 = 0;
            for (unsigned i = tid; i < cntB; i += ST) {
                unsigned bits = cbuf[i];
                if (bits > T) { S2 += __uint_as_float(bits); c2++; }
            }
            for (int off = 32; off > 0; off >>= 1) {
                S2 += __shfl_down(S2, off, 64);
                c2 += __shfl_down(c2, off, 64);
            }
            if (lane == 0) { rs2[wid] = S2; rc2[wid] = c2; }
            __syncthreads();
            if (tid == 0) {
                float S1t = 0.0f, S2t = 0.0f;
                unsigned c2t = 0;
                for (int w = 0; w < NW; ++w) { S1t += rs1[w]; S2t += rs2[w]; c2t += rc2[w]; }
                s_neg = S1t + S2t + (float)(r - (int)c2t) * __uint_as_float(T);
            }
            __syncthreads();
        } else {
            // ---- fallback (collection overflow — practically unreachable): 8-pass global radix ----
            if (tid == 0) { s_prefix = 0u; s_rem = k; }
            __syncthreads();
            for (int pass = 0; pass < 8; ++pass) {
                const int shift = 28 - 4 * pass;
                const unsigned hm = (pass == 0) ? 0u : (0xFFFFFFFFu << (shift + 4));
                const unsigned prefix = s_prefix;
                unsigned cnt[16];
#pragma unroll
                for (int v = 0; v < 16; ++v) cnt[v] = 0u;
                for (int i = tid; i < PP; i += ST) {
                    unsigned bits = __float_as_uint(mv[i]);
                    unsigned key = ((bits & hm) == prefix) ? ((bits >> shift) & 15u) : 16u;
                    if (__any(key != 16u)) {
#pragma unroll
                        for (int v = 0; v < 16; ++v)
                            cnt[v] += (unsigned)__popcll(__ballot(key == (unsigned)v));
                    }
                }
                if (lane == 0) {
#pragma unroll
                    for (int v = 0; v < 16; ++v) swh[wid * 16 + v] = cnt[v];
                }
                __syncthreads();
                if (tid < 16) {
                    unsigned tt = 0;
#pragma unroll
                    for (int w = 0; w < NW; ++w) tt += swh[w * 16 + tid];
                    stot[tid] = tt;
                }
                __syncthreads();
                if (tid == 0) {
                    int rem = s_rem;
                    unsigned cum = 0;
                    int chosen = 0;
                    for (int v = 15; v >= 0; --v) {
                        unsigned c = stot[v];
                        if (cum + c >= (unsigned)rem) { chosen = v; s_rem = rem - (int)cum; break; }
                        cum += c;
                    }
                    s_prefix = prefix | ((unsigned)chosen << shift);
                }
                __syncthreads();
            }
            const unsigned T = s_prefix;
            float sum = 0.0f;
            unsigned cnt = 0;
            for (int i = tid; i < PP; i += ST) {
                float v = mv[i];
                if (__float_as_uint(v) > T) { sum += v; cnt++; }
            }
            for (int off = 32; off > 0; off >>= 1) {
                sum += __shfl_down(sum, off, 64);
                cnt += __shfl_down(cnt, off, 64);
            }
            if (lane == 0) { rs2[wid] = sum; rc2[wid] = cnt; }
            __syncthreads();
            if (tid == 0) {
                float S = 0.0f;
                int G = 0;
                for (int w = 0; w < NW; ++w) { S += rs2[w]; G += (int)rc2[w]; }
                s_neg = S + (float)(k - G) * __uint_as_float(T);
            }
            __syncthreads();
        }
    }

    if (tid == 0) {
        atomicAdd(&acc[0], s_ll);
        atomicAdd(&acc[1], s_lc + s_neg);
        atomicAdd(acc_np, np_b);
        __threadfence();
        unsigned prev = atomicAdd(done, 1u);
        if (prev == BB - 1) {
            int tp = atomicAdd(acc_np, 0);
            float N = (float)max(tp, 1);
            float a0 = atomicAdd(&acc[0], 0.0f);
            float a1 = atomicAdd(&acc[1], 0.0f);
            out[0] = a0 / N;
            out[1] = a1 / N;
        }
    }
}

extern "C" void kernel_launch(void* const* d_in, const int* in_sizes, int n_in,
                              void* d_out, int out_size, void* d_ws, size_t ws_size,
                              hipStream_t stream) {
    const float* loc    = (const float*)d_in[0];
    const float* conf   = (const float*)d_in[1];
    const float* priors = (const float*)d_in[2];
    const float* gt     = (const float*)d_in[3];
    const int*   labels = (const int*)d_in[4];
    float* out = (float*)d_out;

    char* ws = (char*)d_ws;
    const size_t SZ_BP = (size_t)BB * PP * 4;          // 1,231,872 B
    const size_t SZ_SLOT = (size_t)BB * NSLOTW * 4;    // 154,624 B
    // [0,4096) gkey | [4096,4104) acc | [4104,4108) acc_np | [4108,4112) done | pad 4224
    unsigned long long* gkey = (unsigned long long*)ws;
    float*    acc    = (float*)   (ws + 4096);
    int*      acc_np = (int*)     (ws + 4104);
    unsigned* done   = (unsigned*)(ws + 4108);
    unsigned* bp  = (unsigned*)(ws + 4224);
    float* mine = (float*)(ws + 4224 + SZ_BP);
    float* p_ll = (float*)(ws + 4224 + 2 * SZ_BP);
    float* p_lc = (float*)(ws + 4224 + 2 * SZ_BP + SZ_SLOT);
    int*   p_np = (int*)  (ws + 4224 + 2 * SZ_BP + 2 * SZ_SLOT);

    (void)hipMemsetAsync(ws, 0, 4224, stream);   // gkey + acc + acc_np + done

    k_match<<<MBLK, MTB, 0, stream>>>(priors, gt, gkey);

    dim3 pg(NMB, BB);
    k_prior<<<pg, MTB, 0, stream>>>(priors, gt, labels, bp);

    k_force<<<1, 512, 0, stream>>>(labels, gkey, bp);

    dim3 kg(NSLOT, BB);
    k_main<<<kg, MAINB, 0, stream>>>(loc, conf, priors, gt, bp,
                                     mine, p_ll, p_lc, p_np);

    k_select<<<BB, ST, 0, stream>>>(mine, p_ll, p_lc, p_np, acc, acc_np, done, out);
}